// Round 1
// baseline (7003.757 us; speedup 1.0000x reference)
//
#include <hip/hip_runtime.h>
#include <hip/hip_bf16.h>
#include <cstdint>

static constexpr int HWPIX = 16384;   // 128*128
static constexpr int NCH   = 512;
static constexpr int NCHUNK = 32;     // gram pixel-axis split
static constexpr int CHUNK  = HWPIX / NCHUNK;  // 512

// ---------------- conv + bias + relu, direct, 4 pixels/thread ----------------
template<int K>
__global__ __launch_bounds__(256) void conv_relu_k(
    const float* __restrict__ x, const float* __restrict__ wgt,
    const float* __restrict__ bias, float* __restrict__ feat, int cbase)
{
    constexpr int P  = (K - 1) / 2;
    constexpr int NX = K + 3;                    // x window for 4 outputs
    const int tid  = threadIdx.x;
    const int pix0 = blockIdx.x * 1024 + tid * 4; // 4 consecutive pixels, same row
    const int h    = pix0 >> 7;
    const int w0   = pix0 & 127;
    const int co   = blockIdx.y;                 // channel within this filter group
    const int b    = blockIdx.z;

    __shared__ float wsm[3 * K * K];
    for (int i = tid; i < 3 * K * K; i += 256) wsm[i] = wgt[co * (3 * K * K) + i];
    __syncthreads();

    float acc0 = 0.f, acc1 = 0.f, acc2 = 0.f, acc3 = 0.f;
    const float* xb = x + (size_t)b * 3 * HWPIX;

    for (int ic = 0; ic < 3; ++ic) {
        const float* xc = xb + ic * HWPIX;
        #pragma unroll 1
        for (int kh = 0; kh < K; ++kh) {
            const int xh = h + kh - P;
            if ((unsigned)xh >= 128u) continue;   // zero padding -> row contributes 0
            const float* xrow = xc + xh * 128;
            const float* wr   = wsm + (ic * K + kh) * K;
            float xr[NX];
            #pragma unroll
            for (int o = 0; o < NX; ++o) {
                const int xw = w0 + o - P;
                float v = 0.f;
                if ((unsigned)xw < 128u) v = xrow[xw];
                xr[o] = v;
            }
            #pragma unroll
            for (int kw = 0; kw < K; ++kw) {
                const float wv = wr[kw];
                acc0 = fmaf(xr[kw + 0], wv, acc0);
                acc1 = fmaf(xr[kw + 1], wv, acc1);
                acc2 = fmaf(xr[kw + 2], wv, acc2);
                acc3 = fmaf(xr[kw + 3], wv, acc3);
            }
        }
    }
    const float bv = bias[co];
    float4 r;
    r.x = fmaxf(acc0 + bv, 0.f);
    r.y = fmaxf(acc1 + bv, 0.f);
    r.z = fmaxf(acc2 + bv, 0.f);
    r.w = fmaxf(acc3 + bv, 0.f);
    *reinterpret_cast<float4*>(feat + (size_t)(b * NCH + cbase + co) * HWPIX + pix0) = r;
}

// ---------------- gram partial: one block = (batch*group, pixel-chunk) ----------------
__global__ __launch_bounds__(256) void gram_partial(
    const float* __restrict__ feat, const int* __restrict__ perm,
    float* __restrict__ part)
{
    const int bg    = blockIdx.y;        // 0..15  (b*8 + g)
    const int b     = bg >> 3;
    const int gq    = bg & 7;
    const int chunk = blockIdx.x;        // 0..NCHUNK-1
    const int n0    = chunk * CHUNK;
    const int tid   = threadIdx.x;

    __shared__ float tile[64][33];       // +1 pad: conflict-free
    __shared__ const float* rowp[64];

    if (tid < 64) {
        const int pc = perm[gq * 64 + tid];
        rowp[tid] = feat + (size_t)(b * NCH + pc) * HWPIX + n0;
    }
    __syncthreads();

    float acc[4][4];
    #pragma unroll
    for (int i = 0; i < 4; ++i)
        #pragma unroll
        for (int j = 0; j < 4; ++j) acc[i][j] = 0.f;

    const int tr = tid >> 4;             // 0..15
    const int tc = tid & 15;             // 0..15

    for (int t = 0; t < CHUNK / 32; ++t) {     // 16 tiles of 32 pixels
        #pragma unroll
        for (int i = 0; i < 8; ++i) {
            const int e  = tid + i * 256;       // 0..2047
            const int ch = e >> 5;
            const int nn = e & 31;
            tile[ch][nn] = rowp[ch][t * 32 + nn];
        }
        __syncthreads();
        #pragma unroll
        for (int nn = 0; nn < 32; ++nn) {
            float a0 = tile[tr * 4 + 0][nn];
            float a1 = tile[tr * 4 + 1][nn];
            float a2 = tile[tr * 4 + 2][nn];
            float a3 = tile[tr * 4 + 3][nn];
            float c0 = tile[tc * 4 + 0][nn];
            float c1 = tile[tc * 4 + 1][nn];
            float c2 = tile[tc * 4 + 2][nn];
            float c3 = tile[tc * 4 + 3][nn];
            acc[0][0] = fmaf(a0, c0, acc[0][0]); acc[0][1] = fmaf(a0, c1, acc[0][1]);
            acc[0][2] = fmaf(a0, c2, acc[0][2]); acc[0][3] = fmaf(a0, c3, acc[0][3]);
            acc[1][0] = fmaf(a1, c0, acc[1][0]); acc[1][1] = fmaf(a1, c1, acc[1][1]);
            acc[1][2] = fmaf(a1, c2, acc[1][2]); acc[1][3] = fmaf(a1, c3, acc[1][3]);
            acc[2][0] = fmaf(a2, c0, acc[2][0]); acc[2][1] = fmaf(a2, c1, acc[2][1]);
            acc[2][2] = fmaf(a2, c2, acc[2][2]); acc[2][3] = fmaf(a2, c3, acc[2][3]);
            acc[3][0] = fmaf(a3, c0, acc[3][0]); acc[3][1] = fmaf(a3, c1, acc[3][1]);
            acc[3][2] = fmaf(a3, c2, acc[3][2]); acc[3][3] = fmaf(a3, c3, acc[3][3]);
        }
        __syncthreads();
    }

    float* pp = part + ((size_t)bg * NCHUNK + chunk) * 4096;
    #pragma unroll
    for (int i = 0; i < 4; ++i)
        #pragma unroll
        for (int j = 0; j < 4; ++j)
            pp[(tr * 4 + i) * 64 + (tc * 4 + j)] = acc[i][j];
}

// ---------------- reduce partials -> output ----------------
__global__ __launch_bounds__(256) void gram_reduce(
    const float* __restrict__ part, float* __restrict__ out)
{
    const int idx = blockIdx.x * 256 + threadIdx.x;   // 0..65535
    const int bg  = idx >> 12;
    const int e   = idx & 4095;
    float s = 0.f;
    #pragma unroll
    for (int c = 0; c < NCHUNK; ++c)
        s += part[((size_t)bg * NCHUNK + c) * 4096 + e];
    out[idx] = s;
}

extern "C" void kernel_launch(void* const* d_in, const int* in_sizes, int n_in,
                              void* d_out, int out_size, void* d_ws, size_t ws_size,
                              hipStream_t stream) {
    const float* x = (const float*)d_in[0];
    const float* w[8];
    const float* bs[8];
    for (int i = 0; i < 8; ++i) {
        w[i]  = (const float*)d_in[1 + 2 * i];
        bs[i] = (const float*)d_in[2 + 2 * i];
    }
    const int* perm = (const int*)d_in[17];

    float* feat = (float*)d_ws;                                   // 2*512*16384 f32 = 64 MiB
    float* part = (float*)((char*)d_ws + (size_t)2 * NCH * HWPIX * sizeof(float)); // 8 MiB
    float* out  = (float*)d_out;

    const dim3 cg(16, 64, 2);
    conv_relu_k< 3><<<cg, 256, 0, stream>>>(x, w[0], bs[0], feat, 0 * 64);
    conv_relu_k< 5><<<cg, 256, 0, stream>>>(x, w[1], bs[1], feat, 1 * 64);
    conv_relu_k< 7><<<cg, 256, 0, stream>>>(x, w[2], bs[2], feat, 2 * 64);
    conv_relu_k<11><<<cg, 256, 0, stream>>>(x, w[3], bs[3], feat, 3 * 64);
    conv_relu_k<15><<<cg, 256, 0, stream>>>(x, w[4], bs[4], feat, 4 * 64);
    conv_relu_k<23><<<cg, 256, 0, stream>>>(x, w[5], bs[5], feat, 5 * 64);
    conv_relu_k<37><<<cg, 256, 0, stream>>>(x, w[6], bs[6], feat, 6 * 64);
    conv_relu_k<55><<<cg, 256, 0, stream>>>(x, w[7], bs[7], feat, 7 * 64);

    gram_partial<<<dim3(NCHUNK, 16), 256, 0, stream>>>(feat, perm, part);
    gram_reduce<<<dim3(65536 / 256), 256, 0, stream>>>(part, out);
}

// Round 2
// 329.410 us; speedup vs baseline: 21.2615x; 21.2615x over previous
//
#include <hip/hip_runtime.h>
#include <hip/hip_bf16.h>
#include <cstdint>

typedef __attribute__((ext_vector_type(8))) short short8;
typedef __attribute__((ext_vector_type(4))) float f32x4;

static constexpr int HWPIX  = 16384;   // 128*128
static constexpr int NCH    = 512;
static constexpr int NCHUNK = 16;      // gram pixel-axis split
static constexpr int CHUNK  = HWPIX / NCHUNK;  // 1024

// bf16 round-to-nearest-even, bit-level (no API dependence)
__device__ __forceinline__ unsigned short f2bf(float f) {
    unsigned int u = __float_as_uint(f);
    u = (u + 0x7fffu + ((u >> 16) & 1u)) >> 16;
    return (unsigned short)u;
}

// K-geometry helpers (all constexpr per filter size)
// K dim order: kw outer, icr=(ic*K+kh) inner, icr padded to SPC*8.
// segment = 8 consecutive icr at fixed kw. 4 segments = one MFMA K-chunk of 32.
template<int K> struct KG {
    static constexpr int SPC  = (3 * K + 7) / 8;      // segments per column
    static constexpr int SEGS = K * SPC;
    static constexpr int NCHK = (SEGS + 3) / 4;       // MFMA K-chunks
    static constexpr int COLS = 64 + K - 1;           // LDS columns (64-px tile)
    static constexpr int SROW = SPC * 8;              // elems per column-row
    static constexpr int XSE  = COLS * SROW + 64;     // + pad for tail-clamp reads
};

// ---------- weight repack: w[co][ic][kh][kw] f32 -> per-chunk/per-thread bf16 ----------
// layout: wpk[chunk t][tid 0..255][8], tid -> co=(tid>>6)*16+(tid&15), seg=t*4+((tid>>4)&3)
template<int K>
__global__ __launch_bounds__(256) void repack_w(const float* __restrict__ w,
                                                unsigned short* __restrict__ wpk)
{
    constexpr int SPC = KG<K>::SPC;
    const int t   = blockIdx.x;
    const int tid = threadIdx.x;
    const int co  = ((tid >> 6) << 4) + (tid & 15);
    const int seg = t * 4 + ((tid >> 4) & 3);
    const int kw  = seg / SPC;
    const int r   = seg - kw * SPC;
    short8 o;
    #pragma unroll
    for (int j = 0; j < 8; ++j) {
        const int icr = r * 8 + j;
        float v = 0.f;
        if (kw < K && icr < 3 * K) {
            const int ic = icr / K;
            const int kh = icr - ic * K;
            v = w[((co * 3 + ic) * K + kh) * K + kw];
        }
        o[j] = (short)f2bf(v);
    }
    *reinterpret_cast<short8*>(wpk + ((size_t)(t * 256 + tid)) * 8) = o;
}

// ---------- conv as implicit GEMM, MFMA 16x16x32 bf16 ----------
// block: 256 thr = 4 waves; output tile 64 co x 64 px (one half image row)
template<int K>
__global__ __launch_bounds__(256) void conv_mfma(
    const float* __restrict__ x, const unsigned short* __restrict__ wpk,
    const float* __restrict__ bias, float* __restrict__ feat, int cbase)
{
    constexpr int P    = (K - 1) / 2;
    constexpr int SPC  = KG<K>::SPC;
    constexpr int NCHK = KG<K>::NCHK;
    constexpr int COLS = KG<K>::COLS;
    constexpr int SROW = KG<K>::SROW;

    __shared__ __align__(16) unsigned short xs[KG<K>::XSE];

    const int tid = threadIdx.x;
    const int gp  = blockIdx.x * 64;       // global pixel base
    const int b   = gp >> 14;
    const int p   = gp & (HWPIX - 1);
    const int h   = p >> 7;
    const int w0  = p & 127;

    // zero-fill xs (incl. padding) so 0-weight * xs is never NaN
    for (int i = tid * 8; i < KG<K>::XSE; i += 256 * 8) {
        uint4 z = make_uint4(0, 0, 0, 0);
        *reinterpret_cast<uint4*>(xs + i) = z;
    }
    __syncthreads();

    // stage receptive field: xs[col][icr], col = n + kw (n=pixel-in-tile)
    const float* xb = x + (size_t)b * 3 * HWPIX;
    for (int idx = tid; idx < 3 * K * COLS; idx += 256) {
        const int icr = idx / COLS;
        const int c   = idx - icr * COLS;
        const int ic  = icr / K;
        const int kh  = icr - ic * K;
        const int row = h + kh - P;
        const int col = w0 + c - P;
        float v = 0.f;
        if ((unsigned)row < 128u && (unsigned)col < 128u)
            v = xb[ic * HWPIX + row * 128 + col];
        xs[c * SROW + icr] = f2bf(v);
    }
    __syncthreads();

    const int lane = tid & 63;
    const int wv   = tid >> 6;     // wave id -> co strip
    const int ln15 = lane & 15;
    const int lg   = lane >> 4;    // k-lane-group 0..3

    f32x4 acc[4] = {};   // 4 N-subtiles of 16 px
    const unsigned short* wbase = wpk + (size_t)tid * 8;

    for (int t = 0; t < NCHK; ++t) {
        short8 a = *reinterpret_cast<const short8*>(wbase + (size_t)t * 2048);
        const int seg = t * 4 + lg;
        int kw = seg / SPC;
        if (kw > K - 1) kw = K - 1;          // tail clamp (weights are 0 there)
        const int r = seg - kw * SPC;
        const unsigned short* bp = xs + (ln15 + kw) * SROW + r * 8;
        #pragma unroll
        for (int nf = 0; nf < 4; ++nf) {
            short8 bfr = *reinterpret_cast<const short8*>(bp + nf * 16 * SROW);
            acc[nf] = __builtin_amdgcn_mfma_f32_16x16x32_bf16(a, bfr, acc[nf], 0, 0, 0);
        }
    }

    // epilogue: bias + relu, D layout col=lane&15 (pixel), row=(lane>>4)*4+i (co)
    const int costrip = wv * 16;
    #pragma unroll
    for (int nf = 0; nf < 4; ++nf) {
        #pragma unroll
        for (int i = 0; i < 4; ++i) {
            const int row = lg * 4 + i;
            const int co  = costrip + row;
            const int pix = p + nf * 16 + ln15;
            float vv = fmaxf(acc[nf][i] + bias[co], 0.f);
            feat[((size_t)(b * NCH + cbase + co)) * HWPIX + pix] = vv;
        }
    }
}

// ---------------- gram partial (unchanged structure, NCHUNK=16) ----------------
__global__ __launch_bounds__(256) void gram_partial(
    const float* __restrict__ feat, const int* __restrict__ perm,
    float* __restrict__ part)
{
    const int bg    = blockIdx.y;        // 0..15  (b*8 + g)
    const int b     = bg >> 3;
    const int gq    = bg & 7;
    const int chunk = blockIdx.x;        // 0..NCHUNK-1
    const int n0    = chunk * CHUNK;
    const int tid   = threadIdx.x;

    __shared__ float tile[64][33];
    __shared__ const float* rowp[64];

    if (tid < 64) {
        const int pc = perm[gq * 64 + tid];
        rowp[tid] = feat + (size_t)(b * NCH + pc) * HWPIX + n0;
    }
    __syncthreads();

    float acc[4][4];
    #pragma unroll
    for (int i = 0; i < 4; ++i)
        #pragma unroll
        for (int j = 0; j < 4; ++j) acc[i][j] = 0.f;

    const int tr = tid >> 4;
    const int tc = tid & 15;

    for (int t = 0; t < CHUNK / 32; ++t) {
        #pragma unroll
        for (int i = 0; i < 8; ++i) {
            const int e  = tid + i * 256;
            const int ch = e >> 5;
            const int nn = e & 31;
            tile[ch][nn] = rowp[ch][t * 32 + nn];
        }
        __syncthreads();
        #pragma unroll
        for (int nn = 0; nn < 32; ++nn) {
            float a0 = tile[tr * 4 + 0][nn];
            float a1 = tile[tr * 4 + 1][nn];
            float a2 = tile[tr * 4 + 2][nn];
            float a3 = tile[tr * 4 + 3][nn];
            float c0 = tile[tc * 4 + 0][nn];
            float c1 = tile[tc * 4 + 1][nn];
            float c2 = tile[tc * 4 + 2][nn];
            float c3 = tile[tc * 4 + 3][nn];
            acc[0][0] = fmaf(a0, c0, acc[0][0]); acc[0][1] = fmaf(a0, c1, acc[0][1]);
            acc[0][2] = fmaf(a0, c2, acc[0][2]); acc[0][3] = fmaf(a0, c3, acc[0][3]);
            acc[1][0] = fmaf(a1, c0, acc[1][0]); acc[1][1] = fmaf(a1, c1, acc[1][1]);
            acc[1][2] = fmaf(a1, c2, acc[1][2]); acc[1][3] = fmaf(a1, c3, acc[1][3]);
            acc[2][0] = fmaf(a2, c0, acc[2][0]); acc[2][1] = fmaf(a2, c1, acc[2][1]);
            acc[2][2] = fmaf(a2, c2, acc[2][2]); acc[2][3] = fmaf(a2, c3, acc[2][3]);
            acc[3][0] = fmaf(a3, c0, acc[3][0]); acc[3][1] = fmaf(a3, c1, acc[3][1]);
            acc[3][2] = fmaf(a3, c2, acc[3][2]); acc[3][3] = fmaf(a3, c3, acc[3][3]);
        }
        __syncthreads();
    }

    float* pp = part + ((size_t)bg * NCHUNK + chunk) * 4096;
    #pragma unroll
    for (int i = 0; i < 4; ++i)
        #pragma unroll
        for (int j = 0; j < 4; ++j)
            pp[(tr * 4 + i) * 64 + (tc * 4 + j)] = acc[i][j];
}

__global__ __launch_bounds__(256) void gram_reduce(
    const float* __restrict__ part, float* __restrict__ out)
{
    const int idx = blockIdx.x * 256 + threadIdx.x;   // 0..65535
    const int bg  = idx >> 12;
    const int e   = idx & 4095;
    float s = 0.f;
    #pragma unroll
    for (int c = 0; c < NCHUNK; ++c)
        s += part[((size_t)bg * NCHUNK + c) * 4096 + e];
    out[idx] = s;
}

extern "C" void kernel_launch(void* const* d_in, const int* in_sizes, int n_in,
                              void* d_out, int out_size, void* d_ws, size_t ws_size,
                              hipStream_t stream) {
    const float* x = (const float*)d_in[0];
    const float* w[8];
    const float* bs[8];
    for (int i = 0; i < 8; ++i) {
        w[i]  = (const float*)d_in[1 + 2 * i];
        bs[i] = (const float*)d_in[2 + 2 * i];
    }
    const int* perm = (const int*)d_in[17];

    // ws layout: feat (64 MiB) | part (4 MiB) | wpk (2.03 MiB)  -> ~70 MiB total
    float* feat = (float*)d_ws;
    float* part = (float*)((char*)d_ws + (size_t)2 * NCH * HWPIX * sizeof(float));
    unsigned short* wpk0 = (unsigned short*)((char*)part + (size_t)16 * NCHUNK * 4096 * sizeof(float));
    float* out  = (float*)d_out;

    // per-filter chunk counts and wpk offsets (in chunks of 256*8 ushorts)
    const int nchk[8] = { KG<3>::NCHK, KG<5>::NCHK, KG<7>::NCHK, KG<11>::NCHK,
                          KG<15>::NCHK, KG<23>::NCHK, KG<37>::NCHK, KG<55>::NCHK };
    size_t off[8];
    size_t acc = 0;
    for (int i = 0; i < 8; ++i) { off[i] = acc * 2048; acc += nchk[i]; }

    repack_w< 3><<<nchk[0], 256, 0, stream>>>(w[0], wpk0 + off[0]);
    repack_w< 5><<<nchk[1], 256, 0, stream>>>(w[1], wpk0 + off[1]);
    repack_w< 7><<<nchk[2], 256, 0, stream>>>(w[2], wpk0 + off[2]);
    repack_w<11><<<nchk[3], 256, 0, stream>>>(w[3], wpk0 + off[3]);
    repack_w<15><<<nchk[4], 256, 0, stream>>>(w[4], wpk0 + off[4]);
    repack_w<23><<<nchk[5], 256, 0, stream>>>(w[5], wpk0 + off[5]);
    repack_w<37><<<nchk[6], 256, 0, stream>>>(w[6], wpk0 + off[6]);
    repack_w<55><<<nchk[7], 256, 0, stream>>>(w[7], wpk0 + off[7]);

    const int nblk = (2 * HWPIX) / 64;   // 512
    conv_mfma< 3><<<nblk, 256, 0, stream>>>(x, wpk0 + off[0], bs[0], feat, 0 * 64);
    conv_mfma< 5><<<nblk, 256, 0, stream>>>(x, wpk0 + off[1], bs[1], feat, 1 * 64);
    conv_mfma< 7><<<nblk, 256, 0, stream>>>(x, wpk0 + off[2], bs[2], feat, 2 * 64);
    conv_mfma<11><<<nblk, 256, 0, stream>>>(x, wpk0 + off[3], bs[3], feat, 3 * 64);
    conv_mfma<15><<<nblk, 256, 0, stream>>>(x, wpk0 + off[4], bs[4], feat, 4 * 64);
    conv_mfma<23><<<nblk, 256, 0, stream>>>(x, wpk0 + off[5], bs[5], feat, 5 * 64);
    conv_mfma<37><<<nblk, 256, 0, stream>>>(x, wpk0 + off[6], bs[6], feat, 6 * 64);
    conv_mfma<55><<<nblk, 256, 0, stream>>>(x, wpk0 + off[7], bs[7], feat, 7 * 64);

    gram_partial<<<dim3(NCHUNK, 16), 256, 0, stream>>>(feat, perm, part);
    gram_reduce<<<dim3(65536 / 256), 256, 0, stream>>>(part, out);
}

// Round 4
// 151.327 us; speedup vs baseline: 46.2822x; 2.1768x over previous
//
#include <hip/hip_runtime.h>
#include <hip/hip_bf16.h>
#include <cstdint>

typedef __attribute__((ext_vector_type(8))) short short8;
typedef __attribute__((ext_vector_type(4))) float f32x4;

static constexpr int HWPIX = 16384;   // 128*128
static constexpr int NCH   = 512;
static constexpr int GCHK  = 32;      // gram pixel chunks (512 px each)

__device__ __forceinline__ unsigned short f2bf(float f) {
    unsigned int u = __float_as_uint(f);
    u = (u + 0x7fffu + ((u >> 16) & 1u)) >> 16;
    return (unsigned short)u;
}

// K-dim order: kw outer, icr=(ic*K+kh) inner, padded to SPC*8.
template<int K> struct KG {
    static constexpr int SPC  = (3 * K + 7) / 8;
    static constexpr int SEGS = K * SPC;
    static constexpr int NCHK = (SEGS + 3) / 4;
    static constexpr int COLS = 64 + K - 1;
    static constexpr int SROW = SPC * 8;
    static constexpr int XSE  = COLS * SROW;
};

struct PtrArgs {
    const float* w[8];
    const float* bias[8];
    unsigned short* wpk[8];
    int cum[9];
};

// ---------------- fused weight repack ----------------
template<int K>
__device__ void repack_body(const float* __restrict__ w, unsigned short* __restrict__ wpk, int t) {
    constexpr int SPC = KG<K>::SPC;
    const int tid = threadIdx.x;
    const int co  = ((tid >> 6) << 4) + (tid & 15);
    const int seg = t * 4 + ((tid >> 4) & 3);
    const int kw  = seg / SPC;
    const int r   = seg - kw * SPC;
    short8 o;
    #pragma unroll
    for (int j = 0; j < 8; ++j) {
        const int icr = r * 8 + j;
        float v = 0.f;
        if (kw < K && icr < 3 * K) {
            const int ic = icr / K;
            const int kh = icr - ic * K;
            v = w[((co * 3 + ic) * K + kh) * K + kw];
        }
        o[j] = (short)f2bf(v);
    }
    *reinterpret_cast<short8*>(wpk + ((size_t)(t * 256 + tid)) * 8) = o;
}

__global__ __launch_bounds__(256) void repack_all(PtrArgs a) {
    const int blk = blockIdx.x;
    int f = 0;
    #pragma unroll
    for (int i = 0; i < 8; ++i) if (blk >= a.cum[i + 1]) f = i + 1;
    const int t = blk - a.cum[f];
    switch (f) {
        case 0: repack_body< 3>(a.w[0], a.wpk[0], t); break;
        case 1: repack_body< 5>(a.w[1], a.wpk[1], t); break;
        case 2: repack_body< 7>(a.w[2], a.wpk[2], t); break;
        case 3: repack_body<11>(a.w[3], a.wpk[3], t); break;
        case 4: repack_body<15>(a.w[4], a.wpk[4], t); break;
        case 5: repack_body<23>(a.w[5], a.wpk[5], t); break;
        case 6: repack_body<37>(a.w[6], a.wpk[6], t); break;
        case 7: repack_body<55>(a.w[7], a.wpk[7], t); break;
    }
}

// ---------------- fused conv, implicit-GEMM MFMA ----------------
template<int K>
__device__ void conv_body(const float* __restrict__ x, const unsigned short* __restrict__ wpk,
                          const float* __restrict__ bias, unsigned short* __restrict__ feat,
                          int cbase, unsigned short* xs, int bx)
{
    constexpr int P    = (K - 1) / 2;
    constexpr int SPC  = KG<K>::SPC;
    constexpr int SEGS = KG<K>::SEGS;
    constexpr int NCHK = KG<K>::NCHK;
    constexpr int COLS = KG<K>::COLS;
    constexpr int SROW = KG<K>::SROW;

    const int tid = threadIdx.x;
    const int gp  = bx * 64;
    const int b   = gp >> 14;
    const int p   = gp & (HWPIX - 1);
    const int h   = p >> 7;
    const int w0  = p & 127;

    for (int i = tid * 8; i < KG<K>::XSE; i += 256 * 8)
        *reinterpret_cast<uint4*>(xs + i) = make_uint4(0, 0, 0, 0);
    __syncthreads();

    const float* xb = x + (size_t)b * 3 * HWPIX;
    for (int idx = tid; idx < 3 * K * COLS; idx += 256) {
        const int icr = idx / COLS;
        const int c   = idx - icr * COLS;
        const int ic  = icr / K;
        const int kh  = icr - ic * K;
        const int row = h + kh - P;
        const int col = w0 + c - P;
        float v = 0.f;
        if ((unsigned)row < 128u && (unsigned)col < 128u)
            v = xb[ic * HWPIX + row * 128 + col];
        xs[c * SROW + icr] = f2bf(v);
    }
    __syncthreads();

    const int lane = tid & 63;
    const int wv   = tid >> 6;
    const int ln15 = lane & 15;
    const int lg   = lane >> 4;

    f32x4 acc[4] = {};
    const unsigned short* wbase = wpk + (size_t)tid * 8;

    for (int t = 0; t < NCHK; ++t) {
        short8 a = *reinterpret_cast<const short8*>(wbase + (size_t)t * 2048);
        const int seg = t * 4 + lg;
        int kw = 0, r = 0;
        if (seg < SEGS) {                 // tail segs: weights are 0, read seg 0
            kw = seg / SPC;
            r  = seg - kw * SPC;
        }
        const unsigned short* bp = xs + (ln15 + kw) * SROW + r * 8;
        #pragma unroll
        for (int nf = 0; nf < 4; ++nf) {
            short8 bfr = *reinterpret_cast<const short8*>(bp + nf * 16 * SROW);
            acc[nf] = __builtin_amdgcn_mfma_f32_16x16x32_bf16(a, bfr, acc[nf], 0, 0, 0);
        }
    }

    const int costrip = wv * 16;
    #pragma unroll
    for (int nf = 0; nf < 4; ++nf) {
        #pragma unroll
        for (int i = 0; i < 4; ++i) {
            const int co  = costrip + lg * 4 + i;
            const int pix = p + nf * 16 + ln15;
            float vv = fmaxf(acc[nf][i] + bias[co], 0.f);
            feat[((size_t)(b * NCH + cbase + co)) * HWPIX + pix] = f2bf(vv);
        }
    }
}

__global__ __launch_bounds__(256) void conv_all(const float* __restrict__ x,
                                                PtrArgs a, unsigned short* __restrict__ feat)
{
    __shared__ __align__(16) unsigned short xs[KG<55>::XSE];
    switch (blockIdx.y) {
        case 0: conv_body< 3>(x, a.wpk[0], a.bias[0], feat, 0 * 64, xs, blockIdx.x); break;
        case 1: conv_body< 5>(x, a.wpk[1], a.bias[1], feat, 1 * 64, xs, blockIdx.x); break;
        case 2: conv_body< 7>(x, a.wpk[2], a.bias[2], feat, 2 * 64, xs, blockIdx.x); break;
        case 3: conv_body<11>(x, a.wpk[3], a.bias[3], feat, 3 * 64, xs, blockIdx.x); break;
        case 4: conv_body<15>(x, a.wpk[4], a.bias[4], feat, 4 * 64, xs, blockIdx.x); break;
        case 5: conv_body<23>(x, a.wpk[5], a.bias[5], feat, 5 * 64, xs, blockIdx.x); break;
        case 6: conv_body<37>(x, a.wpk[6], a.bias[6], feat, 6 * 64, xs, blockIdx.x); break;
        case 7: conv_body<55>(x, a.wpk[7], a.bias[7], feat, 7 * 64, xs, blockIdx.x); break;
    }
}

// ---------------- gram via MFMA ----------------
// grid (GCHK=32 chunks of 512px, 16 bg); 2 staging passes of 256 px each.
__global__ __launch_bounds__(256) void gram_mfma(
    const unsigned short* __restrict__ feat, const int* __restrict__ perm,
    float* __restrict__ part)
{
    __shared__ __align__(16) unsigned short tile[64 * 256];
    __shared__ int permch[64];

    const int bg = blockIdx.y, chunk = blockIdx.x;
    const int b = bg >> 3, gq = bg & 7;
    const int tid = threadIdx.x;

    if (tid < 64) permch[tid] = perm[gq * 64 + tid];
    __syncthreads();

    const int lane = tid & 63;
    const int wv   = tid >> 6;
    const int ln15 = lane & 15;
    const int kg   = lane >> 4;

    f32x4 acc[4] = {};
    const size_t pxbase = (size_t)chunk * 512;

    for (int p2 = 0; p2 < 2; ++p2) {
        {
            const int r0 = tid >> 5;        // 0..7
            const int g  = tid & 31;        // 16B group 0..31
            #pragma unroll
            for (int it = 0; it < 8; ++it) {
                const int r = it * 8 + r0;
                const unsigned short* src =
                    feat + (((size_t)(b * NCH + permch[r])) << 14) + pxbase + p2 * 256 + g * 8;
                short8 v = *reinterpret_cast<const short8*>(src);
                *reinterpret_cast<short8*>(tile + r * 256 + ((g ^ (r & 7)) * 8)) = v;
            }
        }
        __syncthreads();
        #pragma unroll
        for (int t = 0; t < 8; ++t) {
            const int g  = t * 4 + kg;
            const int ra = wv * 16 + ln15;
            short8 av = *reinterpret_cast<const short8*>(tile + ra * 256 + ((g ^ (ra & 7)) * 8));
            #pragma unroll
            for (int cs = 0; cs < 4; ++cs) {
                const int rb = cs * 16 + ln15;
                short8 bv = *reinterpret_cast<const short8*>(tile + rb * 256 + ((g ^ (rb & 7)) * 8));
                acc[cs] = __builtin_amdgcn_mfma_f32_16x16x32_bf16(av, bv, acc[cs], 0, 0, 0);
            }
        }
        __syncthreads();
    }

    float* pp = part + ((size_t)bg * GCHK + chunk) * 4096;
    #pragma unroll
    for (int cs = 0; cs < 4; ++cs)
        #pragma unroll
        for (int i = 0; i < 4; ++i) {
            const int row = wv * 16 + kg * 4 + i;
            const int col = cs * 16 + ln15;
            pp[row * 64 + col] = acc[cs][i];
        }
}

__global__ __launch_bounds__(256) void gram_reduce(
    const float* __restrict__ part, float* __restrict__ out)
{
    const int idx = blockIdx.x * 256 + threadIdx.x;   // 0..65535
    const int bg  = idx >> 12;
    const int e   = idx & 4095;
    const float* p = part + (size_t)bg * GCHK * 4096 + e;
    float s = 0.f;
    #pragma unroll
    for (int c = 0; c < GCHK; ++c) s += p[c * 4096];
    out[idx] = s;
}

extern "C" void kernel_launch(void* const* d_in, const int* in_sizes, int n_in,
                              void* d_out, int out_size, void* d_ws, size_t ws_size,
                              hipStream_t stream) {
    const float* x = (const float*)d_in[0];
    const int* perm = (const int*)d_in[17];

    // ws: feat bf16 32MiB | part 8MiB | wpk ~2.03MiB  -> ~42 MiB
    unsigned short* feat = (unsigned short*)d_ws;
    float* part = (float*)((char*)d_ws + (size_t)2 * NCH * HWPIX * sizeof(unsigned short));
    unsigned short* wpk0 = (unsigned short*)((char*)part + (size_t)16 * GCHK * 4096 * sizeof(float));
    float* out = (float*)d_out;

    const int nchk[8] = { KG<3>::NCHK, KG<5>::NCHK, KG<7>::NCHK, KG<11>::NCHK,
                          KG<15>::NCHK, KG<23>::NCHK, KG<37>::NCHK, KG<55>::NCHK };
    PtrArgs a;
    int acc = 0;
    for (int i = 0; i < 8; ++i) {
        a.w[i]    = (const float*)d_in[1 + 2 * i];
        a.bias[i] = (const float*)d_in[2 + 2 * i];
        a.wpk[i]  = wpk0 + (size_t)acc * 2048;
        a.cum[i]  = acc;
        acc += nchk[i];
    }
    a.cum[8] = acc;   // 519 total chunks

    repack_all<<<acc, 256, 0, stream>>>(a);
    conv_all<<<dim3(512, 8), 256, 0, stream>>>(x, a, feat);
    gram_mfma<<<dim3(GCHK, 16), 256, 0, stream>>>(feat, perm, part);
    gram_reduce<<<dim3(65536 / 256), 256, 0, stream>>>(part, out);
}